// Round 1
// baseline (7619.527 us; speedup 1.0000x reference)
//
#include <hip/hip_runtime.h>
#include <cstddef>

// BasicRNN: outs[b,t,o], hs[b,t,h]
//   pre   = obs_t @ W_in^T + b_in + h @ W_h^T + b_h
//   h_new = 0.5*relu(pre) + 0.5*h
//   out   = h_new @ W_out^T + b_out
//
// Decomposition:
//   Phase A (parallel): X[b,t,:] = obs[b,t,:] @ W_in^T + b_in + b_h   -> written into hs region of d_out
//   Phase B (sequential, persistent kernel): h recurrence, X slot overwritten in place by h_t
//   Phase C (parallel): outs = hs @ W_out^T + b_out

static constexpr int Bb = 64;
static constexpr int Tt = 512;
static constexpr int Dd = 256;
static constexpr int Hh = 1024;
static constexpr int Oo = 256;

// ---------------------------------------------------------------- init:
// copy h0 into ping buffer, zero the team barrier counters (ws is re-poisoned
// to 0xAA before every timed launch, so this must run every call).
__global__ __launch_bounds__(256) void init_kernel(const float* __restrict__ h0,
                                                   float* __restrict__ hping,
                                                   unsigned int* __restrict__ cnt)
{
    const int b = blockIdx.x;   // 64 blocks, one batch row each
    const int t = threadIdx.x;  // 256 threads * 4 floats = 1024
    float4 v = *(const float4*)&h0[b * Hh + t * 4];
    *(float4*)&hping[b * Hh + t * 4] = v;
    if (b == 0) cnt[t] = 0u;    // 256 uints covers 4 teams * 64-uint stride
}

// ---------------------------------------------------------------- fp32 GEMM
// C[m][n] = sum_k A[m][k] * Bt[n][k] + bias1[n] (+ bias2[n])
// 128x128 block tile, 256 threads, 8x8 register tile, K-tile 16.
// LDS stride 17 (pad +1): A reads 4 addrs {0,8,16,24} banks (free broadcast),
// B column groups split as [tx*4..] and [64+tx*4..] -> 2-way worst (free).
__global__ __launch_bounds__(256) void gemm_bt_kernel(const float* __restrict__ A,
                                                      const float* __restrict__ Bt,
                                                      const float* __restrict__ bias1,
                                                      const float* __restrict__ bias2,
                                                      float* __restrict__ C,
                                                      int M, int N, int K)
{
    __shared__ float As[128 * 17];
    __shared__ float Bs[128 * 17];
    const int tid = threadIdx.x;
    const int nTiles = N >> 7;
    const int mt = blockIdx.x / nTiles;
    const int nt = blockIdx.x - mt * nTiles;
    const int m0 = mt << 7, n0 = nt << 7;
    const int tx = tid & 15, ty = tid >> 4;

    const int row = tid >> 1;        // 0..127 (two threads per row)
    const int c8  = (tid & 1) << 3;  // float offset 0 or 8 within the 16-wide k tile

    float acc[8][8] = {};

    for (int kt = 0; kt < K; kt += 16) {
        const float4 a0 = *(const float4*)&A [(size_t)(m0 + row) * K + kt + c8];
        const float4 a1 = *(const float4*)&A [(size_t)(m0 + row) * K + kt + c8 + 4];
        const float4 b0 = *(const float4*)&Bt[(size_t)(n0 + row) * K + kt + c8];
        const float4 b1 = *(const float4*)&Bt[(size_t)(n0 + row) * K + kt + c8 + 4];
        __syncthreads();  // previous iteration's LDS reads complete before overwrite
        {
            const int ab = row * 17 + c8;
            As[ab + 0] = a0.x; As[ab + 1] = a0.y; As[ab + 2] = a0.z; As[ab + 3] = a0.w;
            As[ab + 4] = a1.x; As[ab + 5] = a1.y; As[ab + 6] = a1.z; As[ab + 7] = a1.w;
            Bs[ab + 0] = b0.x; Bs[ab + 1] = b0.y; Bs[ab + 2] = b0.z; Bs[ab + 3] = b0.w;
            Bs[ab + 4] = b1.x; Bs[ab + 5] = b1.y; Bs[ab + 6] = b1.z; Bs[ab + 7] = b1.w;
        }
        __syncthreads();
#pragma unroll
        for (int kk = 0; kk < 16; ++kk) {
            float af[8], bf[8];
#pragma unroll
            for (int i = 0; i < 8; ++i) af[i] = As[(ty * 8 + i) * 17 + kk];
#pragma unroll
            for (int j = 0; j < 4; ++j) bf[j] = Bs[(tx * 4 + j) * 17 + kk];
#pragma unroll
            for (int j = 0; j < 4; ++j) bf[4 + j] = Bs[(64 + tx * 4 + j) * 17 + kk];
#pragma unroll
            for (int i = 0; i < 8; ++i) {
#pragma unroll
                for (int j = 0; j < 8; ++j) {
                    acc[i][j] = fmaf(af[i], bf[j], acc[i][j]);
                }
            }
        }
    }

    float bs[8];
#pragma unroll
    for (int j = 0; j < 4; ++j) {
        const int n1 = n0 + tx * 4 + j;
        const int n2 = n0 + 64 + tx * 4 + j;
        bs[j]     = bias1[n1] + (bias2 ? bias2[n1] : 0.0f);
        bs[4 + j] = bias1[n2] + (bias2 ? bias2[n2] : 0.0f);
    }
#pragma unroll
    for (int i = 0; i < 8; ++i) {
        const int m = m0 + ty * 8 + i;
        float4 v0 = make_float4(acc[i][0] + bs[0], acc[i][1] + bs[1],
                                acc[i][2] + bs[2], acc[i][3] + bs[3]);
        float4 v1 = make_float4(acc[i][4] + bs[4], acc[i][5] + bs[5],
                                acc[i][6] + bs[6], acc[i][7] + bs[7]);
        *(float4*)&C[(size_t)m * N + n0 + tx * 4]      = v0;
        *(float4*)&C[(size_t)m * N + n0 + 64 + tx * 4] = v1;
    }
}

// ---------------------------------------------------------------- recurrence
// Persistent kernel. 256 blocks = 4 teams x 64 wgs. Team = 16 batch rows
// (independent across teams). wg owns 16 rows of W_h, fp32-resident in LDS.
// Per step: stage team h (64 KB) -> LDS, 16x16x1024 contraction with K split
// over 16 thread groups, in-wave shuffle reduce over the 4 kg per wave, LDS
// reduce over 4 waves, blend, write h to pong buffer + hs output (in-place
// over the X slot), one release-arrive / acquire-spin team barrier.
// LDS = 2*16*1028*4 + 4*260*4 = 135744 B > 81920 -> hard 1 block/CU, grid
// 256 <= 256 CUs -> all blocks co-resident -> spin barrier is safe.
__global__ __launch_bounds__(256) void rnn_kernel(float* __restrict__ Xhs,   // [64][512][1024]
                                                  float* __restrict__ hA,    // ping [64][1024]
                                                  float* __restrict__ hB,    // pong
                                                  unsigned int* __restrict__ cnt,
                                                  const float* __restrict__ Wh)
{
    __shared__ float Wl[16 * 1028];  // 16 W_h rows, stride pad +4 keeps f4 align, banks (16rg+4i+4k)
    __shared__ float hl[16 * 1028];  // 16 batch rows of h
    __shared__ float red[4 * 260];   // per-wave partials [wave][pair]

    const int tid  = threadIdx.x;
    const int bid  = blockIdx.x;
    const int team = bid & 3;        // bid%8 = XCD round robin -> team spans 2 XCDs
    const int wg   = bid >> 2;       // 0..63 within team
    const int r0   = wg << 4;        // 16 W_h rows
    const int b0   = team << 4;      // 16 batch rows

    // one-time: W slice -> LDS
#pragma unroll
    for (int it = 0; it < 16; ++it) {
        const int idx = it * 256 + tid;
        const int i   = idx >> 8;
        const int c4  = idx & 255;
        float4 w = *(const float4*)&Wh[(size_t)(r0 + i) * Hh + c4 * 4];
        *(float4*)&Wl[i * 1028 + c4 * 4] = w;
    }

    const int kg   = tid >> 4;   // 0..15  K-chunk of 64
    const int pg   = tid & 15;
    const int rg   = pg >> 2;    // 0..3   row group (4 rows)
    const int bg   = pg & 3;     // 0..3   batch group (4 rows)
    const int wv   = tid >> 6;   // wave id
    const int lane = tid & 63;

    unsigned int* mycnt = cnt + team * 64;  // 256 B apart per team

    for (int t = 0; t < Tt; ++t) {
        // ---- team barrier: wait for all 64 wgs to have published h(t)
        if (t > 0 && tid == 0) {
            const unsigned int target = (unsigned int)t * 64u;
            while (__hip_atomic_load(mycnt, __ATOMIC_RELAXED, __HIP_MEMORY_SCOPE_AGENT) < target) {
            }
            __builtin_amdgcn_fence(__ATOMIC_ACQUIRE, "agent");  // invalidate stale L1/L2
        }
        __syncthreads();  // also protects hl/red against next-step overwrite

        const float* __restrict__ hcur = (t & 1) ? hB : hA;
        float* __restrict__ hnxt       = (t & 1) ? hA : hB;

        // ---- stage h(t) for team batches into LDS
#pragma unroll
        for (int it = 0; it < 16; ++it) {
            const int idx = it * 256 + tid;
            const int j   = idx >> 8;
            const int c4  = idx & 255;
            float4 v = *(const float4*)&hcur[(size_t)(b0 + j) * Hh + c4 * 4];
            *(float4*)&hl[j * 1028 + c4 * 4] = v;
        }
        __syncthreads();

        // ---- partial contraction: acc[j:batch][i:row] over k in [kg*64, kg*64+64)
        float acc[4][4] = {};
        {
            const int kbase = kg << 6;
            const float* wp[4];
            const float* hp[4];
#pragma unroll
            for (int i = 0; i < 4; ++i) wp[i] = &Wl[(rg * 4 + i) * 1028 + kbase];
#pragma unroll
            for (int j = 0; j < 4; ++j) hp[j] = &hl[(bg * 4 + j) * 1028 + kbase];
#pragma unroll
            for (int kk = 0; kk < 16; ++kk) {
                // kg-phase rotation -> worst-case 2-way bank conflict (free)
                const int ko = ((kk + kg) & 15) << 2;
                float4 wvv[4], hvv[4];
#pragma unroll
                for (int i = 0; i < 4; ++i) wvv[i] = *(const float4*)(wp[i] + ko);
#pragma unroll
                for (int j = 0; j < 4; ++j) hvv[j] = *(const float4*)(hp[j] + ko);
#pragma unroll
                for (int j = 0; j < 4; ++j) {
#pragma unroll
                    for (int i = 0; i < 4; ++i) {
                        acc[j][i] = fmaf(wvv[i].x, hvv[j].x, acc[j][i]);
                        acc[j][i] = fmaf(wvv[i].y, hvv[j].y, acc[j][i]);
                        acc[j][i] = fmaf(wvv[i].z, hvv[j].z, acc[j][i]);
                        acc[j][i] = fmaf(wvv[i].w, hvv[j].w, acc[j][i]);
                    }
                }
            }
        }

        // ---- reduce the 4 kg per wave via shuffles (lanes ^16, ^32 share pg)
#pragma unroll
        for (int j = 0; j < 4; ++j) {
#pragma unroll
            for (int i = 0; i < 4; ++i) {
                float v = acc[j][i];
                v += __shfl_xor(v, 16, 64);
                v += __shfl_xor(v, 32, 64);
                acc[j][i] = v;
            }
        }
        if (lane < 16) {
#pragma unroll
            for (int j = 0; j < 4; ++j) {
#pragma unroll
                for (int i = 0; i < 4; ++i) {
                    const int pair = (bg * 4 + j) * 16 + (rg * 4 + i);
                    red[wv * 260 + pair] = acc[j][i];
                }
            }
        }
        __syncthreads();

        // ---- finalize: one (batch,row) pair per thread
        {
            const int b_l = tid >> 4;
            const int r_l = tid & 15;
            float s = red[0 * 260 + tid] + red[1 * 260 + tid] +
                      red[2 * 260 + tid] + red[3 * 260 + tid];
            const int gb = b0 + b_l;
            const int gr = r0 + r_l;
            const size_t xi = ((size_t)gb * Tt + t) * Hh + gr;
            const float x     = Xhs[xi];               // X slot: read once...
            const float hprev = hl[b_l * 1028 + gr];
            const float pre   = s + x;
            const float hn    = 0.5f * fmaxf(pre, 0.0f) + 0.5f * hprev;
            Xhs[xi] = hn;                              // ...then becomes hs output
            hnxt[(size_t)gb * Hh + gr] = hn;
        }
        __syncthreads();  // all stores vmcnt-drained before the release arrive
        if (tid == 0) {
            __hip_atomic_fetch_add(mycnt, 1u, __ATOMIC_RELEASE, __HIP_MEMORY_SCOPE_AGENT);
        }
    }
}

// ---------------------------------------------------------------- launch
extern "C" void kernel_launch(void* const* d_in, const int* in_sizes, int n_in,
                              void* d_out, int out_size, void* d_ws, size_t ws_size,
                              hipStream_t stream)
{
    (void)in_sizes; (void)n_in; (void)out_size; (void)ws_size;

    const float* obs  = (const float*)d_in[0];  // [64][512][256]
    const float* h0   = (const float*)d_in[1];  // [64][1024]
    const float* Win  = (const float*)d_in[2];  // [1024][256]
    const float* bin  = (const float*)d_in[3];  // [1024]
    const float* Wh   = (const float*)d_in[4];  // [1024][1024]
    const float* bh   = (const float*)d_in[5];  // [1024]
    const float* Wout = (const float*)d_in[6];  // [256][1024]
    const float* bout = (const float*)d_in[7];  // [256]

    float* outs = (float*)d_out;                   // [64][512][256]
    float* hs   = outs + (size_t)Bb * Tt * Oo;     // [64][512][1024] (doubles as X)

    float* hping      = (float*)d_ws;              // [64][1024]
    float* hpong      = hping + Bb * Hh;           // [64][1024]
    unsigned int* cnt = (unsigned int*)(hpong + Bb * Hh);  // 4 teams * 64-uint stride

    init_kernel<<<64, 256, 0, stream>>>(h0, hping, cnt);

    // Phase A: X = obs @ W_in^T + b_in + b_h  -> hs region
    gemm_bt_kernel<<<(Bb * Tt / 128) * (Hh / 128), 256, 0, stream>>>(
        obs, Win, bin, bh, hs, Bb * Tt, Hh, Dd);

    // Phase B: sequential recurrence (in-place X -> hs)
    rnn_kernel<<<256, 256, 0, stream>>>(hs, hping, hpong, cnt, Wh);

    // Phase C: outs = hs @ W_out^T + b_out
    gemm_bt_kernel<<<(Bb * Tt / 128) * (Oo / 128), 256, 0, stream>>>(
        hs, Wout, bout, nullptr, outs, Bb * Tt, Oo, Hh);
}

// Round 2
// 3461.088 us; speedup vs baseline: 2.2015x; 2.2015x over previous
//
#include <hip/hip_runtime.h>
#include <cstddef>

// BasicRNN, Round 2.
// Phase A (parallel): X = obs @ W_in^T + b_in + b_h  -> hs region of d_out
// Phase B (persistent): recurrence. 4 teams x 64 wgs; wg = 16 rows of W_h
//   (bf16 in LDS), team = 16 batch rows. Per step one mfma_f32_16x16x32_bf16
//   16x16 tile per wave (K split over 4 waves), fp32 h master state in
//   registers (thread owns its (b,r) forever), bf16 h broadcast through the
//   coherence point via RELAXED+AGENT atomics (no fences, no L2 inv/wb),
//   flag-array barrier (1 relaxed store/wg + 64-lane gather poll).
// Phase C (parallel): outs = hs @ W_out^T + b_out

static constexpr int Bb = 64;
static constexpr int Tt = 512;
static constexpr int Dd = 256;
static constexpr int Hh = 1024;
static constexpr int Oo = 256;

typedef __attribute__((ext_vector_type(8))) short bf16x8;
typedef __attribute__((ext_vector_type(4))) float f32x4;
typedef unsigned long long ull;

// fp32 -> bf16 (RNE, inputs are well-behaved: no NaN/Inf)
static __device__ __forceinline__ unsigned short f2b(float f) {
    unsigned int u = __float_as_uint(f);
    u = (u + 0x7fffu + ((u >> 16) & 1u)) >> 16;
    return (unsigned short)u;
}

// ---------------------------------------------------------------- init:
// zero the 256 barrier flags (ws is re-poisoned to 0xAA before every call).
__global__ __launch_bounds__(256) void init_kernel(unsigned int* __restrict__ flags)
{
    flags[threadIdx.x] = 0u;
}

// ---------------------------------------------------------------- fp32 GEMM
// (unchanged from round 1 — known good, ~340 us for phases A+C)
__global__ __launch_bounds__(256) void gemm_bt_kernel(const float* __restrict__ A,
                                                      const float* __restrict__ Bt,
                                                      const float* __restrict__ bias1,
                                                      const float* __restrict__ bias2,
                                                      float* __restrict__ C,
                                                      int M, int N, int K)
{
    __shared__ float As[128 * 17];
    __shared__ float Bs[128 * 17];
    const int tid = threadIdx.x;
    const int nTiles = N >> 7;
    const int mt = blockIdx.x / nTiles;
    const int nt = blockIdx.x - mt * nTiles;
    const int m0 = mt << 7, n0 = nt << 7;
    const int tx = tid & 15, ty = tid >> 4;

    const int row = tid >> 1;
    const int c8  = (tid & 1) << 3;

    float acc[8][8] = {};

    for (int kt = 0; kt < K; kt += 16) {
        const float4 a0 = *(const float4*)&A [(size_t)(m0 + row) * K + kt + c8];
        const float4 a1 = *(const float4*)&A [(size_t)(m0 + row) * K + kt + c8 + 4];
        const float4 b0 = *(const float4*)&Bt[(size_t)(n0 + row) * K + kt + c8];
        const float4 b1 = *(const float4*)&Bt[(size_t)(n0 + row) * K + kt + c8 + 4];
        __syncthreads();
        {
            const int ab = row * 17 + c8;
            As[ab + 0] = a0.x; As[ab + 1] = a0.y; As[ab + 2] = a0.z; As[ab + 3] = a0.w;
            As[ab + 4] = a1.x; As[ab + 5] = a1.y; As[ab + 6] = a1.z; As[ab + 7] = a1.w;
            Bs[ab + 0] = b0.x; Bs[ab + 1] = b0.y; Bs[ab + 2] = b0.z; Bs[ab + 3] = b0.w;
            Bs[ab + 4] = b1.x; Bs[ab + 5] = b1.y; Bs[ab + 6] = b1.z; Bs[ab + 7] = b1.w;
        }
        __syncthreads();
#pragma unroll
        for (int kk = 0; kk < 16; ++kk) {
            float af[8], bf[8];
#pragma unroll
            for (int i = 0; i < 8; ++i) af[i] = As[(ty * 8 + i) * 17 + kk];
#pragma unroll
            for (int j = 0; j < 4; ++j) bf[j] = Bs[(tx * 4 + j) * 17 + kk];
#pragma unroll
            for (int j = 0; j < 4; ++j) bf[4 + j] = Bs[(64 + tx * 4 + j) * 17 + kk];
#pragma unroll
            for (int i = 0; i < 8; ++i) {
#pragma unroll
                for (int j = 0; j < 8; ++j) {
                    acc[i][j] = fmaf(af[i], bf[j], acc[i][j]);
                }
            }
        }
    }

    float bs[8];
#pragma unroll
    for (int j = 0; j < 4; ++j) {
        const int n1 = n0 + tx * 4 + j;
        const int n2 = n0 + 64 + tx * 4 + j;
        bs[j]     = bias1[n1] + (bias2 ? bias2[n1] : 0.0f);
        bs[4 + j] = bias1[n2] + (bias2 ? bias2[n2] : 0.0f);
    }
#pragma unroll
    for (int i = 0; i < 8; ++i) {
        const int m = m0 + ty * 8 + i;
        float4 v0 = make_float4(acc[i][0] + bs[0], acc[i][1] + bs[1],
                                acc[i][2] + bs[2], acc[i][3] + bs[3]);
        float4 v1 = make_float4(acc[i][4] + bs[4], acc[i][5] + bs[5],
                                acc[i][6] + bs[6], acc[i][7] + bs[7]);
        *(float4*)&C[(size_t)m * N + n0 + tx * 4]      = v0;
        *(float4*)&C[(size_t)m * N + n0 + 64 + tx * 4] = v1;
    }
}

// ---------------------------------------------------------------- recurrence
// 256 blocks, 256 threads. LDS ~71 KB. All 256 blocks co-resident (grid <=
// 256 CUs even at 1 block/CU) -> spin barrier deadlock-free.
//
// MFMA 16x16x32 bf16 operand layout (gfx950, HW-verified per guide):
//   A: lane l holds A[m=l&15][k = (l>>4)*8 + j], j=0..7   (8 consecutive k)
//   B: lane l holds B[k = (l>>4)*8 + j][n=l&15]
//   D: lane l reg i -> D[row=(l>>4)*4+i][col=l&15]
// We compute pre[b][r] = sum_k h[b][k] * W[r][k]:
//   A[m=b][k] = h_bf16[b][k] from hl, B[k][n=r] = W[r][k] from Wl.
// Both fragments are one ds_read_b128 of 8 consecutive bf16 from a row.
// Wl fragments are loop-invariant -> hoisted to registers (32 VGPRs).
__global__ __launch_bounds__(256) void rnn_kernel(float* __restrict__ Xhs,   // [64][512][1024]
                                                  const float* __restrict__ h0,
                                                  const float* __restrict__ Wh,
                                                  ull* __restrict__ hx,      // [2][64][256] (bf16x4)
                                                  unsigned int* __restrict__ flags) // [4][64]
{
    __shared__ short Wl[16 * 1032];  // 16 W_h rows bf16, stride 1032 (516 dw, %32==4: conflict-free b128)
    __shared__ short hl[16 * 1032];  // 16 batch rows of h, bf16
    __shared__ float red[4 * 272];   // per-wave partial C tiles, stride 17
    __shared__ short hxl[256];       // 16x16 bf16 publish staging

    const int tid  = threadIdx.x;
    const int bid  = blockIdx.x;
    const int team = bid & 3;        // bid%8 = XCD round-robin -> team spans 2 XCDs
    const int wg   = bid >> 2;       // 0..63
    const int r0   = wg << 4;        // 16 W_h rows
    const int b0   = team << 4;      // 16 batch rows

    const int lane = tid & 63;
    const int wv   = tid >> 6;
    // fragment address (shorts): row (l&15), k base = wv*256 + (l>>4)*8
    const int frag_off = (lane & 15) * 1032 + (wv << 8) + ((lane >> 4) << 3);

    // ---- one-time: W slice fp32 -> bf16 -> LDS
#pragma unroll
    for (int it = 0; it < 16; ++it) {
        const int idx = it * 256 + tid;   // [0,4096) float4-chunks
        const int i   = idx >> 8;
        const int c4  = idx & 255;
        const float4 w = *(const float4*)&Wh[(size_t)(r0 + i) * Hh + c4 * 4];
        ull p = (ull)f2b(w.x) | ((ull)f2b(w.y) << 16) | ((ull)f2b(w.z) << 32) | ((ull)f2b(w.w) << 48);
        *(ull*)&Wl[i * 1032 + c4 * 4] = p;
    }
    // ---- t=0: h0 slice fp32 -> bf16 -> LDS
#pragma unroll
    for (int it = 0; it < 16; ++it) {
        const int idx = it * 256 + tid;
        const int b   = idx >> 8;
        const int c4  = idx & 255;
        const float4 v = *(const float4*)&h0[(size_t)(b0 + b) * Hh + c4 * 4];
        ull p = (ull)f2b(v.x) | ((ull)f2b(v.y) << 16) | ((ull)f2b(v.z) << 32) | ((ull)f2b(v.w) << 48);
        *(ull*)&hl[b * 1032 + c4 * 4] = p;
    }
    __syncthreads();

    // hoist loop-invariant W fragments into registers
    bf16x8 wfrag[8];
#pragma unroll
    for (int s = 0; s < 8; ++s) {
        wfrag[s] = *(const bf16x8*)(Wl + frag_off + s * 32);
    }

    // fp32 master h state: this thread owns (b = tid>>4, r = tid&15) forever
    const int tb = tid >> 4, tr = tid & 15;
    float hprev = h0[(size_t)(b0 + tb) * Hh + r0 + tr];
    const size_t xbase = ((size_t)(b0 + tb) * Tt) * Hh + (r0 + tr);
    float xr = Xhs[xbase];   // x for t=0

    for (int t = 0; t < Tt; ++t) {
        if (t > 0) {
            // ---- team barrier: poll 64 flags with one 64-lane gather (wave 0)
            if (tid < 64) {
                for (;;) {
                    unsigned int v = __hip_atomic_load(&flags[(team << 6) + lane],
                                                       __ATOMIC_RELAXED, __HIP_MEMORY_SCOPE_AGENT);
                    if (__all((int)(v >= (unsigned int)t))) break;
                }
            }
            __syncthreads();
            __atomic_signal_fence(__ATOMIC_SEQ_CST);
            // ---- stage team h(t) bf16 from coherence point (L1/L2-bypass loads)
            const ull* __restrict__ src = hx + (size_t)(t & 1) * Bb * 256;
#pragma unroll
            for (int it = 0; it < 16; ++it) {
                const int idx = it * 256 + tid;   // [0,4096) ulongs
                const int b   = idx >> 8;         // 256 ulongs per 1024-bf16 row
                const int c   = idx & 255;
                ull v = __hip_atomic_load(&src[(size_t)(b0 + b) * 256 + c],
                                          __ATOMIC_RELAXED, __HIP_MEMORY_SCOPE_AGENT);
                *(ull*)&hl[b * 1032 + c * 4] = v;
            }
            __syncthreads();
        }

        // prefetch next step's x (independent of the recurrence; hides HBM latency)
        const int tn = (t + 1 < Tt) ? (t + 1) : t;
        const float xnext = Xhs[xbase + (size_t)tn * Hh];

        // ---- one 16x16 MFMA tile, K=256 per wave
        f32x4 acc = {0.f, 0.f, 0.f, 0.f};
#pragma unroll
        for (int s = 0; s < 8; ++s) {
            const bf16x8 af = *(const bf16x8*)(hl + frag_off + s * 32);
            acc = __builtin_amdgcn_mfma_f32_16x16x32_bf16(af, wfrag[s], acc, 0, 0, 0);
        }
        // partials -> LDS (D layout: row=(l>>4)*4+i, col=l&15), stride 17 kills conflicts
        {
            const int row0 = (lane >> 4) << 2;
            const int col  = lane & 15;
#pragma unroll
            for (int i = 0; i < 4; ++i) {
                red[wv * 272 + (row0 + i) * 17 + col] = acc[i];
            }
        }
        __syncthreads();

        // ---- finalize: one (b,r) per thread, fp32 chain in registers
        {
            const float s = red[0 * 272 + tb * 17 + tr] + red[1 * 272 + tb * 17 + tr]
                          + red[2 * 272 + tb * 17 + tr] + red[3 * 272 + tb * 17 + tr];
            const float pre = s + xr;
            const float hn  = 0.5f * fmaxf(pre, 0.0f) + 0.5f * hprev;
            hprev = hn;
            Xhs[xbase + (size_t)t * Hh] = hn;      // hs output (fp32)
            hxl[tb * 16 + tr] = (short)f2b(hn);    // bf16 for the broadcast
            xr = xnext;
        }
        __syncthreads();

        // ---- publish 16x16 bf16 block to the other slab (L1/L2-bypass stores)
        if (tid < 64) {
            const int bb = tid >> 2, j = tid & 3;
            const ull v = *(const ull*)&hxl[bb * 16 + j * 4];
            ull* __restrict__ dst = hx + (size_t)((t + 1) & 1) * Bb * 256;
            __hip_atomic_store(&dst[(size_t)(b0 + bb) * 256 + (r0 >> 2) + j], v,
                               __ATOMIC_RELAXED, __HIP_MEMORY_SCOPE_AGENT);
        }
        __syncthreads();   // drains vmcnt: hx stores reach coherence point before flag
        if (tid == 0) {
            __hip_atomic_store(&flags[(team << 6) + wg], (unsigned int)(t + 1),
                               __ATOMIC_RELAXED, __HIP_MEMORY_SCOPE_AGENT);
        }
    }
}

// ---------------------------------------------------------------- launch
extern "C" void kernel_launch(void* const* d_in, const int* in_sizes, int n_in,
                              void* d_out, int out_size, void* d_ws, size_t ws_size,
                              hipStream_t stream)
{
    (void)in_sizes; (void)n_in; (void)out_size; (void)ws_size;

    const float* obs  = (const float*)d_in[0];  // [64][512][256]
    const float* h0   = (const float*)d_in[1];  // [64][1024]
    const float* Win  = (const float*)d_in[2];  // [1024][256]
    const float* bin  = (const float*)d_in[3];  // [1024]
    const float* Wh   = (const float*)d_in[4];  // [1024][1024]
    const float* bh   = (const float*)d_in[5];  // [1024]
    const float* Wout = (const float*)d_in[6];  // [256][1024]
    const float* bout = (const float*)d_in[7];  // [256]

    float* outs = (float*)d_out;                   // [64][512][256]
    float* hs   = outs + (size_t)Bb * Tt * Oo;     // [64][512][1024] (doubles as X)

    ull* hx             = (ull*)d_ws;              // [2][64][256] ulongs = 256 KB
    unsigned int* flags = (unsigned int*)(hx + 2 * (size_t)Bb * 256);  // [4][64]

    init_kernel<<<1, 256, 0, stream>>>(flags);

    // Phase A: X = obs @ W_in^T + b_in + b_h  -> hs region
    gemm_bt_kernel<<<(Bb * Tt / 128) * (Hh / 128), 256, 0, stream>>>(
        obs, Win, bin, bh, hs, Bb * Tt, Hh, Dd);

    // Phase B: sequential recurrence (in-place X -> hs)
    rnn_kernel<<<256, 256, 0, stream>>>(hs, h0, Wh, hx, flags);

    // Phase C: outs = hs @ W_out^T + b_out
    gemm_bt_kernel<<<(Bb * Tt / 128) * (Oo / 128), 256, 0, stream>>>(
        hs, Wout, bout, nullptr, outs, Bb * Tt, Oo, Hh);
}

// Round 3
// 2056.713 us; speedup vs baseline: 3.7047x; 1.6828x over previous
//
#include <hip/hip_runtime.h>
#include <cstddef>

// BasicRNN, Round 3.
// Phase A (parallel): X = obs @ W_in^T + b_in + b_h  -> hs region of d_out
// Phase B (persistent): recurrence, 16 teams x 16 wgs.
//   wg owns 64 rows of W_h as REGISTER-resident bf16 MFMA fragments
//   (32 frags/wave for its 16-row slice). team owns 4 batch rows.
//   Exchange: self-tagged 8B words [3 bf16 | step tag] through relaxed
//   agent-scope atomics, 2-slab ping-pong, NO flags, NO fences, NO drains.
//   Readers poll the data words directly; the observing load IS the payload.
// Phase C (parallel): outs = hs @ W_out^T + b_out

static constexpr int Bb = 64;
static constexpr int Tt = 512;
static constexpr int Dd = 256;
static constexpr int Hh = 1024;
static constexpr int Oo = 256;

typedef __attribute__((ext_vector_type(8))) short bf16x8;
typedef __attribute__((ext_vector_type(4))) float f32x4;
typedef unsigned long long ull;

static __device__ __forceinline__ unsigned short f2b(float f) {
    unsigned int u = __float_as_uint(f);
    u = (u + 0x7fffu + ((u >> 16) & 1u)) >> 16;
    return (unsigned short)u;
}
static __device__ __forceinline__ ull pack4(float a, float b, float c, float d) {
    return (ull)f2b(a) | ((ull)f2b(b) << 16) | ((ull)f2b(c) << 32) | ((ull)f2b(d) << 48);
}

// ---------------------------------------------------------------- fp32 GEMM
// (unchanged from round 1/2 — known good)
__global__ __launch_bounds__(256) void gemm_bt_kernel(const float* __restrict__ A,
                                                      const float* __restrict__ Bt,
                                                      const float* __restrict__ bias1,
                                                      const float* __restrict__ bias2,
                                                      float* __restrict__ C,
                                                      int M, int N, int K)
{
    __shared__ float As[128 * 17];
    __shared__ float Bs[128 * 17];
    const int tid = threadIdx.x;
    const int nTiles = N >> 7;
    const int mt = blockIdx.x / nTiles;
    const int nt = blockIdx.x - mt * nTiles;
    const int m0 = mt << 7, n0 = nt << 7;
    const int tx = tid & 15, ty = tid >> 4;

    const int row = tid >> 1;
    const int c8  = (tid & 1) << 3;

    float acc[8][8] = {};

    for (int kt = 0; kt < K; kt += 16) {
        const float4 a0 = *(const float4*)&A [(size_t)(m0 + row) * K + kt + c8];
        const float4 a1 = *(const float4*)&A [(size_t)(m0 + row) * K + kt + c8 + 4];
        const float4 b0 = *(const float4*)&Bt[(size_t)(n0 + row) * K + kt + c8];
        const float4 b1 = *(const float4*)&Bt[(size_t)(n0 + row) * K + kt + c8 + 4];
        __syncthreads();
        {
            const int ab = row * 17 + c8;
            As[ab + 0] = a0.x; As[ab + 1] = a0.y; As[ab + 2] = a0.z; As[ab + 3] = a0.w;
            As[ab + 4] = a1.x; As[ab + 5] = a1.y; As[ab + 6] = a1.z; As[ab + 7] = a1.w;
            Bs[ab + 0] = b0.x; Bs[ab + 1] = b0.y; Bs[ab + 2] = b0.z; Bs[ab + 3] = b0.w;
            Bs[ab + 4] = b1.x; Bs[ab + 5] = b1.y; Bs[ab + 6] = b1.z; Bs[ab + 7] = b1.w;
        }
        __syncthreads();
#pragma unroll
        for (int kk = 0; kk < 16; ++kk) {
            float af[8], bf[8];
#pragma unroll
            for (int i = 0; i < 8; ++i) af[i] = As[(ty * 8 + i) * 17 + kk];
#pragma unroll
            for (int j = 0; j < 4; ++j) bf[j] = Bs[(tx * 4 + j) * 17 + kk];
#pragma unroll
            for (int j = 0; j < 4; ++j) bf[4 + j] = Bs[(64 + tx * 4 + j) * 17 + kk];
#pragma unroll
            for (int i = 0; i < 8; ++i) {
#pragma unroll
                for (int j = 0; j < 8; ++j) {
                    acc[i][j] = fmaf(af[i], bf[j], acc[i][j]);
                }
            }
        }
    }

    float bs[8];
#pragma unroll
    for (int j = 0; j < 4; ++j) {
        const int n1 = n0 + tx * 4 + j;
        const int n2 = n0 + 64 + tx * 4 + j;
        bs[j]     = bias1[n1] + (bias2 ? bias2[n1] : 0.0f);
        bs[4 + j] = bias1[n2] + (bias2 ? bias2[n2] : 0.0f);
    }
#pragma unroll
    for (int i = 0; i < 8; ++i) {
        const int m = m0 + ty * 8 + i;
        float4 v0 = make_float4(acc[i][0] + bs[0], acc[i][1] + bs[1],
                                acc[i][2] + bs[2], acc[i][3] + bs[3]);
        float4 v1 = make_float4(acc[i][4] + bs[4], acc[i][5] + bs[5],
                                acc[i][6] + bs[6], acc[i][7] + bs[7]);
        *(float4*)&C[(size_t)m * N + n0 + tx * 4]      = v0;
        *(float4*)&C[(size_t)m * N + n0 + 64 + tx * 4] = v1;
    }
}

// ---------------------------------------------------------------- recurrence
// 256 blocks x 256 threads. team = bid&15 (bid%8 XCD round-robin -> team on
// 2 XCDs), wg = bid>>4. LDS ~9 KB, VGPR ~200 -> >=1 block/CU everywhere,
// 256 blocks always co-resident -> polling is deadlock-free.
//
// MFMA 16x16x32 bf16 layout (HW-verified): A: lane l = A[m=l&15][k=(l>>4)*8+j];
// B: lane l = B[k=(l>>4)*8+j][n=l&15]; D: lane l reg i = D[m=(l>>4)*4+i][n=l&15].
// A[m][k] = h[batch m&3][k] (batch rows replicated over m); B[k][n] = W[row][k]
// for row = r0 + wv*16 + n. Valid outputs at m=0..3 -> lanes 0..15, regs 0..3.
//
// Exchange word w of wg j covers flat shorts f=3w..3w+2 of the wg's
// [4 batch][64 row] bf16 block; tag in bits 48..63 = step index of the h it
// carries. Slab: ull hx[2][16 team][16 wg][88] (86 used, pad to 88).
__global__ __launch_bounds__(256, 1) void rnn_kernel(float* __restrict__ Xhs, // [64][512][1024]
                                                     const float* __restrict__ h0,
                                                     const float* __restrict__ Wh,
                                                     ull* __restrict__ hx)
{
    __shared__ short hl[4 * 1032];   // team h, bf16; stride 1032 -> 2-way worst on b128
    __shared__ short hxl[264];       // publish staging, 258 used

    const int tid  = threadIdx.x;
    const int bid  = blockIdx.x;
    const int team = bid & 15;
    const int wg   = bid >> 4;       // 0..15
    const int r0   = wg << 6;        // 64 W_h rows
    const int b0   = team << 2;      // 4 batch rows

    const int lane = tid & 63;
    const int wv   = tid >> 6;

    // ---- one-time: 64-row W slice -> register-resident bf16 B-fragments
    bf16x8 wfrag[32];
    {
        const float* wrow = Wh + (size_t)(r0 + wv * 16 + (lane & 15)) * Hh + ((lane >> 4) << 3);
#pragma unroll
        for (int s = 0; s < 32; ++s) {
            const float4 lo = *(const float4*)(wrow + s * 32);
            const float4 hi = *(const float4*)(wrow + s * 32 + 4);
            bf16x8 w;
            w[0] = (short)f2b(lo.x); w[1] = (short)f2b(lo.y);
            w[2] = (short)f2b(lo.z); w[3] = (short)f2b(lo.w);
            w[4] = (short)f2b(hi.x); w[5] = (short)f2b(hi.y);
            w[6] = (short)f2b(hi.z); w[7] = (short)f2b(hi.w);
            wfrag[s] = w;
        }
    }

    // ---- one-time: h0 -> hl (bf16)
#pragma unroll
    for (int it = 0; it < 4; ++it) {
        const int idx = it * 256 + tid;   // 1024 float4 chunks of [4][1024]
        const int b   = idx >> 8;
        const int c4  = idx & 255;
        const float4 v = *(const float4*)&h0[(size_t)(b0 + b) * Hh + c4 * 4];
        *(ull*)&hl[b * 1032 + c4 * 4] = pack4(v.x, v.y, v.z, v.w);
    }

    // ---- per-thread word assignment (16 wgs x 86 words = 1376)
    const int nw = (tid < 96) ? 6 : 5;
    int soff[6], fb6[6], cb6[6];
#pragma unroll
    for (int j = 0; j < 6; ++j) {
        int q = tid + j * 256; if (q >= 1376) q = 0;  // dummy, never polled
        const int wgj = q / 86;
        const int w   = q - 86 * wgj;
        soff[j] = wgj * 88 + w;
        fb6[j]  = 3 * w;
        cb6[j]  = wgj * 64;
    }

    // ---- extraction-lane state: lane<16 owns (batch i=0..3, row exrow)
    const bool ex    = (lane < 16);
    const int  exrow = r0 + wv * 16 + lane;
    float hprev[4] = {0.f, 0.f, 0.f, 0.f};
    float xr[4]    = {0.f, 0.f, 0.f, 0.f};
    float xn[4]    = {0.f, 0.f, 0.f, 0.f};
    if (ex) {
#pragma unroll
        for (int i = 0; i < 4; ++i) {
            hprev[i] = h0[(size_t)(b0 + i) * Hh + exrow];
            xr[i]    = Xhs[(size_t)(b0 + i) * Tt * Hh + exrow];   // x(0)
        }
    }
    __syncthreads();

    const int a_off = (lane & 3) * 1032 + ((lane >> 4) << 3);

    for (int t = 0; t < Tt; ++t) {
        // ---- pre = h(t) @ W^T : 32 MFMAs in 4 independent chains
        f32x4 acc0 = {0.f, 0.f, 0.f, 0.f}, acc1 = acc0, acc2 = acc0, acc3 = acc0;
#pragma unroll
        for (int s = 0; s < 32; s += 4) {
            acc0 = __builtin_amdgcn_mfma_f32_16x16x32_bf16(
                       *(const bf16x8*)(hl + a_off + (s + 0) * 32), wfrag[s + 0], acc0, 0, 0, 0);
            acc1 = __builtin_amdgcn_mfma_f32_16x16x32_bf16(
                       *(const bf16x8*)(hl + a_off + (s + 1) * 32), wfrag[s + 1], acc1, 0, 0, 0);
            acc2 = __builtin_amdgcn_mfma_f32_16x16x32_bf16(
                       *(const bf16x8*)(hl + a_off + (s + 2) * 32), wfrag[s + 2], acc2, 0, 0, 0);
            acc3 = __builtin_amdgcn_mfma_f32_16x16x32_bf16(
                       *(const bf16x8*)(hl + a_off + (s + 3) * 32), wfrag[s + 3], acc3, 0, 0, 0);
        }
        const f32x4 accs01 = acc0 + acc1;
        const f32x4 accs23 = acc2 + acc3;
        const f32x4 acc    = accs01 + accs23;

        // ---- extract h(t+1) for owned (batch, row), stage bf16 publish block
        float hnew[4] = {0.f, 0.f, 0.f, 0.f};
        if (ex) {
#pragma unroll
            for (int i = 0; i < 4; ++i) {
                const float pre = acc[i] + xr[i];
                hnew[i]  = 0.5f * fmaxf(pre, 0.0f) + 0.5f * hprev[i];
                hprev[i] = hnew[i];
                hxl[i * 64 + wv * 16 + lane] = (short)f2b(hnew[i]);
            }
        }
        __syncthreads();

        if (t + 1 < Tt) {
            ull* __restrict__ slab = hx + ((size_t)((t + 1) & 1) * 16 + team) * (16 * 88);

            // ---- publish FIRST (critical path): 86 self-tagged words
            if (tid < 86) {
                const int f0 = 3 * tid;
                const ull w = (ull)(unsigned short)hxl[f0]
                            | ((ull)(unsigned short)hxl[f0 + 1] << 16)
                            | ((ull)(unsigned short)hxl[f0 + 2] << 32)
                            | ((ull)(unsigned int)(t + 1) << 48);
                __hip_atomic_store(&slab[wg * 88 + tid], w,
                                   __ATOMIC_RELAXED, __HIP_MEMORY_SCOPE_AGENT);
            }
            // ---- off critical path: hs output store + next-x prefetch
            if (ex) {
#pragma unroll
                for (int i = 0; i < 4; ++i)
                    Xhs[((size_t)(b0 + i) * Tt + t) * Hh + exrow] = hnew[i];
#pragma unroll
                for (int i = 0; i < 4; ++i)
                    xn[i] = Xhs[((size_t)(b0 + i) * Tt + (t + 1)) * Hh + exrow];
            }

            // ---- poll team's h(t+1) words; observing load IS the payload
            const unsigned short want = (unsigned short)(t + 1);
            ull  pw[6];
            bool dn[6] = {false, false, false, false, false, false};
            int  rem = nw;
            while (rem > 0) {
#pragma unroll
                for (int j = 0; j < 6; ++j) {
                    if (j < nw && !dn[j]) {
                        pw[j] = __hip_atomic_load(&slab[soff[j]],
                                                  __ATOMIC_RELAXED, __HIP_MEMORY_SCOPE_AGENT);
                    }
                }
#pragma unroll
                for (int j = 0; j < 6; ++j) {
                    if (j < nw && !dn[j] && (unsigned short)(pw[j] >> 48) == want) {
                        dn[j] = true; --rem;
                        const int f0 = fb6[j], cb = cb6[j];
                        const unsigned short s0 = (unsigned short)pw[j];
                        const unsigned short s1 = (unsigned short)(pw[j] >> 16);
                        const unsigned short s2 = (unsigned short)(pw[j] >> 32);
                        if (f0     < 256) hl[((f0    ) >> 6) * 1032 + cb + ((f0    ) & 63)] = (short)s0;
                        if (f0 + 1 < 256) hl[((f0 + 1) >> 6) * 1032 + cb + ((f0 + 1) & 63)] = (short)s1;
                        if (f0 + 2 < 256) hl[((f0 + 2) >> 6) * 1032 + cb + ((f0 + 2) & 63)] = (short)s2;
                    }
                }
            }
            if (ex) {
#pragma unroll
                for (int i = 0; i < 4; ++i) xr[i] = xn[i];
            }
            __syncthreads();   // hl now holds h(t+1)
        } else {
            // last step: just emit hs
            if (ex) {
#pragma unroll
                for (int i = 0; i < 4; ++i)
                    Xhs[((size_t)(b0 + i) * Tt + t) * Hh + exrow] = hnew[i];
            }
        }
    }
}

// ---------------------------------------------------------------- launch
extern "C" void kernel_launch(void* const* d_in, const int* in_sizes, int n_in,
                              void* d_out, int out_size, void* d_ws, size_t ws_size,
                              hipStream_t stream)
{
    (void)in_sizes; (void)n_in; (void)out_size; (void)ws_size;

    const float* obs  = (const float*)d_in[0];  // [64][512][256]
    const float* h0   = (const float*)d_in[1];  // [64][1024]
    const float* Win  = (const float*)d_in[2];  // [1024][256]
    const float* bin  = (const float*)d_in[3];  // [1024]
    const float* Wh   = (const float*)d_in[4];  // [1024][1024]
    const float* bh   = (const float*)d_in[5];  // [1024]
    const float* Wout = (const float*)d_in[6];  // [256][1024]
    const float* bout = (const float*)d_in[7];  // [256]

    float* outs = (float*)d_out;                   // [64][512][256]
    float* hs   = outs + (size_t)Bb * Tt * Oo;     // [64][512][1024] (doubles as X)

    ull* hx = (ull*)d_ws;                          // [2][16][16][88] = 360448 B

    // Phase A: X = obs @ W_in^T + b_in + b_h  -> hs region
    gemm_bt_kernel<<<(Bb * Tt / 128) * (Hh / 128), 256, 0, stream>>>(
        obs, Win, bin, bh, hs, Bb * Tt, Hh, Dd);

    // Phase B: sequential recurrence (in-place X -> hs). Tags ping-pong over
    // 2 slabs; 0xAA ws poison reads as tag 0xAAAA which matches no step.
    rnn_kernel<<<256, 256, 0, stream>>>(hs, h0, Wh, hx);

    // Phase C: outs = hs @ W_out^T + b_out
    gemm_bt_kernel<<<(Bb * Tt / 128) * (Oo / 128), 256, 0, stream>>>(
        hs, Wout, bout, nullptr, outs, Bb * Tt, Oo, Hh);
}